// Round 12
// baseline (113.677 us; speedup 1.0000x reference)
//
#include <hip/hip_runtime.h>

#define NN 100000
#define NE 1250000
#define HD 64
#define BMW 3125            // bitmap words = NN/32
#define HALF4 156250        // (NE/4)/2 int4 elements per half
#define NBS 611             // ceil(HALF4/256) sweep blocks

#define CAP_L3   4096
#define CAP_L2   65536
#define CAP_L1   262144
#define CAP_NL2  4096
#define CAP_NL1  65536

#define TBLK 64             // tail blocks
#define TTPB 1024
#define TNTH (TBLK * TTPB)    // 65536 threads
#define TWAVES (TNTH / 64)    // 1024 waves

// ctrl: 0=cntL3 1=cntL2 2=cntL1 3=cntNL2 4=cntNL1
// B2 = NL2 (in-nbrs of pair), B1 = NL1, B0 = NL0 then UNION (seeded in scan1).
// Cross-kernel visibility via kernel boundaries. Inside k_tail, cross-phase
// mutable data uses agent-scope relaxed atomics + the fence-free gbar
// (validated R4/R5/R10: absmax 0 each time).

__device__ __forceinline__ float ldg_f(const float* p) {
    return __hip_atomic_load(p, __ATOMIC_RELAXED, __HIP_MEMORY_SCOPE_AGENT);
}
__device__ __forceinline__ void stg_f(float* p, float v) {
    __hip_atomic_store(p, v, __ATOMIC_RELAXED, __HIP_MEMORY_SCOPE_AGENT);
}

__device__ __forceinline__ void gbar(unsigned* cnt16, unsigned target) {
    __syncthreads();     // drains vmcnt: this block's stores/atomics at LLC
    if (threadIdx.x == 0) {
        __hip_atomic_fetch_add(&cnt16[(blockIdx.x & 15u) * 16], 1u,
                               __ATOMIC_RELAXED, __HIP_MEMORY_SCOPE_AGENT);
        long guard = 0;
        for (;;) {
            unsigned s = 0;
#pragma unroll
            for (int i = 0; i < 16; ++i)
                s += __hip_atomic_load(&cnt16[i * 16], __ATOMIC_RELAXED,
                                       __HIP_MEMORY_SCOPE_AGENT);
            if (s >= target) break;
            __builtin_amdgcn_s_sleep(1);
            if (++guard > (1L << 22)) break;   // deadlock escape
        }
        asm volatile("" ::: "memory");
    }
    __syncthreads();
}

// sweep: edges into {pair}; mark srcs in B2, append NL2, lazy-zero counters
__global__ __launch_bounds__(256) void k_scan3(
        const int* __restrict__ src, const int* __restrict__ dst,
        const int* __restrict__ pair, unsigned* B2,
        float* cnt_out, float* cnt_in, int* L3, int* NL2, int* ctrl) {
    int t = blockIdx.x * blockDim.x + threadIdx.x;
    int p0 = pair[0], p1 = pair[1];
    if (blockIdx.x == 0 && threadIdx.x == 0) {   // pair in-deg lazy zero
        cnt_in[p0] = 0.f; cnt_in[p1] = 0.f;      // benign 0-write races only
    }
    if (t >= HALF4) return;
    int4 a = ((const int4*)dst)[t];              // two independent loads
    int4 b = ((const int4*)dst)[t + HALF4];
#pragma unroll
    for (int h = 0; h < 2; ++h) {
        int4 d4 = h ? b : a;
        int base = (h ? (t + HALF4) : t) * 4;
#pragma unroll
        for (int k = 0; k < 4; ++k) {
            int d = (k == 0) ? d4.x : (k == 1) ? d4.y : (k == 2) ? d4.z : d4.w;
            if (d == p0 || d == p1) {
                int e = base + k, s = src[e];
                int idx = atomicAdd(&ctrl[0], 1);
                if (idx < CAP_L3) L3[idx] = e;
                unsigned m = 1u << (s & 31);
                unsigned old = atomicOr(&B2[s >> 5], m);
                if (!(old & m)) {
                    cnt_out[s] = 0.f; cnt_in[s] = 0.f;
                    int j = atomicAdd(&ctrl[3], 1);
                    if (j < CAP_NL2) NL2[j] = s;
                }
            }
        }
    }
}

// sweep: dst-bit in B2 -> collect L2, set B1/NL1, lazy-zero
__global__ __launch_bounds__(256) void k_scan2(
        const int* __restrict__ src, const int* __restrict__ dst,
        const unsigned* __restrict__ B2, unsigned* B1,
        float* cnt_out, float* cnt_in, int* L2, int* NL1, int* ctrl) {
    int t = blockIdx.x * blockDim.x + threadIdx.x;
    if (t >= HALF4) return;
    int4 a = ((const int4*)dst)[t];
    int4 b = ((const int4*)dst)[t + HALF4];
#pragma unroll
    for (int h = 0; h < 2; ++h) {
        int4 d4 = h ? b : a;
        int base = (h ? (t + HALF4) : t) * 4;
#pragma unroll
        for (int k = 0; k < 4; ++k) {
            int d = (k == 0) ? d4.x : (k == 1) ? d4.y : (k == 2) ? d4.z : d4.w;
            if ((B2[d >> 5] >> (d & 31)) & 1u) {
                int e = base + k, s = src[e];
                int idx = atomicAdd(&ctrl[1], 1);
                if (idx < CAP_L2) L2[idx] = e;
                unsigned m = 1u << (s & 31);
                unsigned old = atomicOr(&B1[s >> 5], m);
                if (!(old & m)) {
                    cnt_out[s] = 0.f; cnt_in[s] = 0.f;
                    int j = atomicAdd(&ctrl[4], 1);
                    if (j < CAP_NL1) NL1[j] = s;
                }
            }
        }
    }
}

// sweep: dst-bit in B1 -> collect L1, set B0, lazy-zero cnt_out.
// Prologue: (a) seeds B0 |= B1|B2 (B0 ends as UNION; double-zero idempotent),
// (b) zeroes agg1 rows (NL1 final here), (c) zeroes agg2 rows (NL2 final).
__global__ __launch_bounds__(256) void k_scan1(
        const int* __restrict__ src, const int* __restrict__ dst,
        const unsigned* __restrict__ B1s, const unsigned* __restrict__ B2,
        unsigned* B0, float* cnt_out, float* bufA, float* bufB,
        const int* __restrict__ NL1, const int* __restrict__ NL2,
        int* L1, int* ctrl) {
    int t = blockIdx.x * blockDim.x + threadIdx.x;
    for (int i = t; i < BMW; i += NBS * 256) {
        unsigned u = B1s[i] | B2[i];
        if (u) atomicOr(&B0[i], u);
    }
    {
        int n1 = min(ctrl[4], CAP_NL1);
        int n2 = min(ctrl[3], CAP_NL2);
        float4 zz = make_float4(0.f, 0.f, 0.f, 0.f);
        for (int i = t; i < (n1 + n2) * 16; i += NBS * 256) {
            int r = i >> 4, c = (i & 15) * 4;
            if (r < n1) *(float4*)&bufB[NL1[r] * HD + c] = zz;
            else        *(float4*)&bufA[NL2[r - n1] * HD + c] = zz;
        }
    }
    if (t >= HALF4) return;
    int4 a = ((const int4*)dst)[t];
    int4 b = ((const int4*)dst)[t + HALF4];
#pragma unroll
    for (int h = 0; h < 2; ++h) {
        int4 d4 = h ? b : a;
        int base = (h ? (t + HALF4) : t) * 4;
#pragma unroll
        for (int k = 0; k < 4; ++k) {
            int d = (k == 0) ? d4.x : (k == 1) ? d4.y : (k == 2) ? d4.z : d4.w;
            if ((B1s[d >> 5] >> (d & 31)) & 1u) {
                int e = base + k, s = src[e];
                int idx = atomicAdd(&ctrl[2], 1);
                if (idx < CAP_L1) L1[idx] = e;
                unsigned m = 1u << (s & 31);
                unsigned old = atomicOr(&B0[s >> 5], m);
                if (!(old & m)) cnt_out[s] = 0.f;
            }
        }
    }
}

// 64-block tail: P0 outdeg-sweep+indeg | P1 scatter1 | P2 gemm1 | P3 scatter2 |
// P4 gemm2 | P5 scatter3 | P6 (block0) gemm3+MLP. 6 fence-free gbars.
// cnt_out/cnt_in/bufA/bufB/x3buf are produced in-kernel -> all later reads use
// agent-scope ldg (stale-L2 hazard after fusion); lists/bitmaps/weights are
// final pre-launch -> plain cached loads.
__global__ __launch_bounds__(TTPB) void k_tail(
        const int* __restrict__ src, const int* __restrict__ dst,
        const int* __restrict__ pair,
        const int* __restrict__ z, const float* __restrict__ zt,
        const float* __restrict__ W1, const float* __restrict__ b1,
        const float* __restrict__ W2, const float* __restrict__ b2,
        const float* __restrict__ W3, const float* __restrict__ b3,
        const float* __restrict__ l1w, const float* __restrict__ l1b,
        const float* __restrict__ l2w, const float* __restrict__ l2b,
        float* out, float* bufA, float* bufB, float* x3buf,
        float* cnt_out, float* cnt_in,
        const unsigned* __restrict__ B0, const unsigned* __restrict__ B1,
        const unsigned* __restrict__ B2,
        const int* __restrict__ L3, const int* __restrict__ L2,
        const int* __restrict__ L1,
        const int* __restrict__ NL2, const int* __restrict__ NL1,
        const int* __restrict__ ctrl, unsigned* cnt16) {
    __shared__ float arow[16][HD];   // wave-private row staging (R9-proven)
    __shared__ float xls[2 * HD];
    __shared__ int cnts[8];
    const int tid = threadIdx.x, blk = blockIdx.x;
    const int gtid = blk * TTPB + tid;
    const int wv = tid >> 6, ln = tid & 63;
    const int gw = gtid >> 6;                    // 0..1023 global wave
    const int p0 = pair[0], p1 = pair[1];

    if (tid < 5) cnts[tid] = ctrl[tid];
    __syncthreads();
    const int e3 = min(cnts[0], CAP_L3), e2 = min(cnts[1], CAP_L2);
    const int e1 = min(cnts[2], CAP_L1);
    const int n2 = min(cnts[3], CAP_NL2), n1 = min(cnts[4], CAP_NL1);

    // ---- P0: out-deg sweep over union B0 + deduped in-deg ----
    for (int t = gtid; t < HALF4; t += TNTH) {
        int4 a = ((const int4*)src)[t];
        int4 b = ((const int4*)src)[t + HALF4];
#pragma unroll
        for (int h = 0; h < 2; ++h) {
            int4 s4 = h ? b : a;
#pragma unroll
            for (int k = 0; k < 4; ++k) {
                int s = (k == 0) ? s4.x : (k == 1) ? s4.y : (k == 2) ? s4.z : s4.w;
                if ((B0[s >> 5] >> (s & 31)) & 1u) atomicAdd(&cnt_out[s], 1.0f);
            }
        }
    }
    for (int t = gtid; t < e1 + e2 + e3; t += TNTH) {
        int e, which;
        if (t < e1)            { e = L1[t];           which = 1; }
        else if (t < e1 + e2)  { e = L2[t - e1];      which = 2; }
        else                   { e = L3[t - e1 - e2]; which = 3; }
        int d = dst[e];
        bool inB1 = (B1[d >> 5] >> (d & 31)) & 1u;
        bool count;
        if (which == 1)      count = true;
        else if (which == 2) count = !inB1;
        else                 count = !inB1 && !((B2[d >> 5] >> (d & 31)) & 1u);
        if (count) atomicAdd(&cnt_in[d], 1.0f);
    }
    gbar(cnt16, 1u * TBLK);

    // ---- P1: scatter1 — agg1[d] += w0(s) * zt[z[s]] (x0 fused) ----
    for (int r = gw; r < e1; r += TWAVES) {
        int e = L1[r], s = src[e], d = dst[e];
        float w0 = 1.0f / sqrtf(fmaxf(ldg_f(&cnt_out[s]), 1.0f));
        atomicAdd(&bufB[d * HD + ln], w0 * zt[z[s] * HD + ln]);
    }
    gbar(cnt16, 2u * TBLK);

    // ---- P2: gemm1 — x1 = relu((agg1*nin)@W1+b1), in-place in bufB ----
    for (int r = gw; r < n1; r += TWAVES) {
        int v = NL1[r];
        float nin = 1.0f / sqrtf(fmaxf(ldg_f(&cnt_in[v]), 1.0f));
        arow[wv][ln] = ldg_f(&bufB[v * HD + ln]) * nin;
        float acc = b1[ln];
#pragma unroll
        for (int i = 0; i < HD; ++i)
            acc += arow[wv][i] * W1[i * HD + ln];
        stg_f(&bufB[v * HD + ln], fmaxf(acc, 0.0f));
    }
    gbar(cnt16, 3u * TBLK);

    // ---- P3: scatter2 — agg2[d] += w0(s) * x1[s] ----
    for (int r = gw; r < e2; r += TWAVES) {
        int e = L2[r], s = src[e], d = dst[e];
        float w0 = 1.0f / sqrtf(fmaxf(ldg_f(&cnt_out[s]), 1.0f));
        atomicAdd(&bufA[d * HD + ln], w0 * ldg_f(&bufB[s * HD + ln]));
    }
    gbar(cnt16, 4u * TBLK);

    // ---- P4: gemm2 — x2 = relu((agg2*nin)@W2+b2), in-place in bufA ----
    for (int r = gw; r < n2; r += TWAVES) {
        int v = NL2[r];
        float nin = 1.0f / sqrtf(fmaxf(ldg_f(&cnt_in[v]), 1.0f));
        arow[wv][ln] = ldg_f(&bufA[v * HD + ln]) * nin;
        float acc = b2[ln];
#pragma unroll
        for (int i = 0; i < HD; ++i)
            acc += arow[wv][i] * W2[i * HD + ln];
        stg_f(&bufA[v * HD + ln], fmaxf(acc, 0.0f));
    }
    gbar(cnt16, 5u * TBLK);

    // ---- P5: scatter3 — x3buf rows {p0,p1} += w0(s) * x2[s] ----
    // (x3buf zeroed by the memset node each replay)
    for (int r = gw; r < e3; r += TWAVES) {
        int e = L3[r], s = src[e], d = dst[e];
        float w0 = 1.0f / sqrtf(fmaxf(ldg_f(&cnt_out[s]), 1.0f));
        float c = w0 * ldg_f(&bufA[s * HD + ln]);
        if (d == p0)             atomicAdd(&x3buf[ln], c);
        if (d == p1 && p1 != p0) atomicAdd(&x3buf[HD + ln], c);
    }
    gbar(cnt16, 6u * TBLK);

    // ---- P6 (block 0): gemm3 (no relu) + final MLP ----
    if (blk != 0) return;
    if (tid < 128) {
        int pv = wv ? p1 : p0;
        int rs = (wv && p1 != p0) ? 1 : 0;       // p0==p1: both use row 0
        float nin = 1.0f / sqrtf(fmaxf(ldg_f(&cnt_in[pv]), 1.0f));
        arow[wv][ln] = ldg_f(&x3buf[rs * HD + ln]) * nin;
        float acc = b3[ln];
#pragma unroll
        for (int i = 0; i < HD; ++i)
            acc += arow[wv][i] * W3[i * HD + ln];
        xls[wv * HD + ln] = acc;
    }
    __syncthreads();
    if (tid < 64) {
        arow[0][tid] = xls[tid] * xls[HD + tid];   // h
        float t2 = l1b[tid];
#pragma unroll
        for (int i = 0; i < HD; ++i)
            t2 += arow[0][i] * l1w[i * HD + tid];
        t2 = fmaxf(t2, 0.0f);
        float val = t2 * l2w[tid];
#pragma unroll
        for (int off = 32; off; off >>= 1)
            val += __shfl_down(val, off, 64);
        if (tid == 0) out[0] = val + l2b[0];
    }
}

extern "C" void kernel_launch(void* const* d_in, const int* in_sizes, int n_in,
                              void* d_out, int out_size, void* d_ws, size_t ws_size,
                              hipStream_t stream) {
    const int*   z    = (const int*)d_in[0];
    const int*   src  = (const int*)d_in[1];
    const int*   dst  = (const int*)d_in[2];
    const int*   pair = (const int*)d_in[3];
    const float* zt   = (const float*)d_in[4];
    const float* W1   = (const float*)d_in[5];
    const float* b1   = (const float*)d_in[6];
    const float* W2   = (const float*)d_in[7];
    const float* b2   = (const float*)d_in[8];
    const float* W3   = (const float*)d_in[9];
    const float* b3   = (const float*)d_in[10];
    const float* l1w  = (const float*)d_in[11];
    const float* l1b  = (const float*)d_in[12];
    const float* l2w  = (const float*)d_in[13];
    const float* l2b  = (const float*)d_in[14];
    float* out = (float*)d_out;

    char* w = (char*)d_ws;
    auto alloc = [&](size_t bytes) {
        char* p = w;
        w += (bytes + 255) & ~(size_t)255;
        return p;
    };
    // contiguous memset region: [cnt16 | ctrl | x3buf | B0 | B1 | B2]
    unsigned* cnt16   = (unsigned*)alloc(1024);
    int*      ctrl    = (int*)alloc(256);
    float*    x3buf   = (float*)alloc(2 * HD * 4);
    unsigned* B0      = (unsigned*)alloc((size_t)BMW * 4);
    unsigned* B1      = (unsigned*)alloc((size_t)BMW * 4);
    unsigned* B2      = (unsigned*)alloc((size_t)BMW * 4);
    char*     zend    = w;
    float*    bufA    = (float*)alloc((size_t)NN * HD * 4);
    float*    bufB    = (float*)alloc((size_t)NN * HD * 4);
    float*    cnt_out = (float*)alloc((size_t)NN * 4);
    float*    cnt_in  = (float*)alloc((size_t)NN * 4);
    int*      L3      = (int*)alloc((size_t)CAP_L3 * 4);
    int*      L2      = (int*)alloc((size_t)CAP_L2 * 4);
    int*      L1      = (int*)alloc((size_t)CAP_L1 * 4);
    int*      NL2     = (int*)alloc((size_t)CAP_NL2 * 4);
    int*      NL1     = (int*)alloc((size_t)CAP_NL1 * 4);

    dim3 b(256);

    hipMemsetAsync(cnt16, 0, (size_t)(zend - (char*)cnt16), stream);
    k_scan3<<<NBS, b, 0, stream>>>(src, dst, pair, B2, cnt_out, cnt_in, L3, NL2, ctrl);
    k_scan2<<<NBS, b, 0, stream>>>(src, dst, B2, B1, cnt_out, cnt_in, L2, NL1, ctrl);
    k_scan1<<<NBS, b, 0, stream>>>(src, dst, B1, B2, B0, cnt_out, bufA, bufB,
                                   NL1, NL2, L1, ctrl);
    k_tail<<<TBLK, TTPB, 0, stream>>>(src, dst, pair, z, zt,
                                      W1, b1, W2, b2, W3, b3,
                                      l1w, l1b, l2w, l2b, out,
                                      bufA, bufB, x3buf, cnt_out, cnt_in,
                                      B0, B1, B2, L3, L2, L1, NL2, NL1,
                                      ctrl, cnt16);
}